// Round 9
// baseline (90.473 us; speedup 1.0000x reference)
//
#include <hip/hip_runtime.h>
#include <hip/hip_bf16.h>
#include <stdint.h>

#define D_MODEL 256
#define NHEAD   8
#define DK      32
#define BATCH   4
#define SEQ     2048
#define MROWS   (BATCH*SEQ)   // 8192

typedef float  f32x4  __attribute__((ext_vector_type(4)));
typedef __bf16 bf16x8 __attribute__((ext_vector_type(8)));

__device__ __forceinline__ unsigned short f2bf(float f) {
  unsigned int u = __float_as_uint(f);
  unsigned int r = (u + 0x7FFFu + ((u >> 16) & 1u)) >> 16;
  return (unsigned short)r;
}
__device__ __forceinline__ float bfbits2f(unsigned short b) {
  return __uint_as_float(((unsigned int)b) << 16);
}

__device__ __forceinline__ f32x4 mfma16(bf16x8 a, bf16x8 b, f32x4 c) {
  return __builtin_amdgcn_mfma_f32_16x16x32_bf16(a, b, c, 0, 0, 0);
}
__device__ __forceinline__ unsigned int cvtpk(float lo, float hi) {
  unsigned int r;
  asm("v_cvt_pk_bf16_f32 %0, %1, %2" : "=v"(r) : "v"(lo), "v"(hi));
  return r;
}

// scale folded into Wq/bq: (1/sqrt(32)) * log2(e)
#define QSCALE 0.2550599440097021f

// ---------------- prep: W fp32->bf16 casts + coordinate weights --------------
__global__ void prep_kernel(const float* __restrict__ cx,
                            const float* __restrict__ Wq, const float* __restrict__ Wk,
                            const float* __restrict__ Wv, const float* __restrict__ Wo,
                            unsigned short* __restrict__ Wqb, unsigned short* __restrict__ Wkb,
                            unsigned short* __restrict__ Wvb, unsigned short* __restrict__ Wob,
                            unsigned short* __restrict__ wb) {
  int tid = blockIdx.x * blockDim.x + threadIdx.x;
  int nthr = gridDim.x * blockDim.x;
  const int nw4 = (D_MODEL * D_MODEL) / 4;  // 16384
  for (int i = tid; i < nw4; i += nthr) {
    float4 a = reinterpret_cast<const float4*>(Wq)[i];
    ushort4 oa; oa.x = f2bf(a.x * QSCALE); oa.y = f2bf(a.y * QSCALE);
    oa.z = f2bf(a.z * QSCALE); oa.w = f2bf(a.w * QSCALE);
    reinterpret_cast<ushort4*>(Wqb)[i] = oa;
    float4 b = reinterpret_cast<const float4*>(Wk)[i];
    ushort4 ob; ob.x = f2bf(b.x); ob.y = f2bf(b.y); ob.z = f2bf(b.z); ob.w = f2bf(b.w);
    reinterpret_cast<ushort4*>(Wkb)[i] = ob;
    float4 c = reinterpret_cast<const float4*>(Wv)[i];
    ushort4 oc; oc.x = f2bf(c.x); oc.y = f2bf(c.y); oc.z = f2bf(c.z); oc.w = f2bf(c.w);
    reinterpret_cast<ushort4*>(Wvb)[i] = oc;
    float4 d = reinterpret_cast<const float4*>(Wo)[i];
    ushort4 od; od.x = f2bf(d.x); od.y = f2bf(d.y); od.z = f2bf(d.z); od.w = f2bf(d.w);
    reinterpret_cast<ushort4*>(Wob)[i] = od;
  }
  for (int i = tid; i < SEQ; i += nthr)
    wb[i] = (i == 0) ? (unsigned short)0 : f2bf(fabsf(cx[i] - cx[i - 1]));
}

// ---------------- fused QKV projection GEMM (x cast fused in staging) --------
// Q/K out: [bh][s][32]; V out: transposed + w-scaled: Vt[bh][d][s] = w_s * V[s][d].
__global__ __launch_bounds__(256) void qkv_gemm(
    const float* __restrict__ x,
    const unsigned short* __restrict__ Wqb, const unsigned short* __restrict__ Wkb,
    const unsigned short* __restrict__ Wvb,
    const float* __restrict__ bq, const float* __restrict__ bk_, const float* __restrict__ bv,
    const unsigned short* __restrict__ wb,
    unsigned short* __restrict__ Qb, unsigned short* __restrict__ Kb, unsigned short* __restrict__ Vt) {
  __shared__ __align__(16) unsigned short As[128 * 72];
  __shared__ __align__(16) unsigned short Bs[128 * 72];
  const int tid = threadIdx.x, lane = tid & 63, wid = tid >> 6;
  const int bm = blockIdx.x * 128;
  const int mat = blockIdx.y >> 1;
  const int ncol = (blockIdx.y & 1) * 128;
  const unsigned short* Wb = (mat == 0) ? Wqb : ((mat == 1) ? Wkb : Wvb);
  const float* bias = (mat == 0) ? bq : ((mat == 1) ? bk_ : bv);
  const float bscale = (mat == 0) ? QSCALE : 1.0f;
  const int waveM = (wid >> 1) * 64, waveN = (wid & 1) * 64;

  f32x4 acc[4][4] = {};
  for (int kt = 0; kt < 4; ++kt) {
    __syncthreads();
#pragma unroll
    for (int p = 0; p < 4; ++p) {
      int c = p * 256 + tid;
      int r = c >> 3, kc = c & 7;
      const float* xp = x + (size_t)(bm + r) * 256 + kt * 64 + kc * 8;
      float4 f0 = *reinterpret_cast<const float4*>(xp);
      float4 f1 = *reinterpret_cast<const float4*>(xp + 4);
      ushort4 h0, h1;
      h0.x = f2bf(f0.x); h0.y = f2bf(f0.y); h0.z = f2bf(f0.z); h0.w = f2bf(f0.w);
      h1.x = f2bf(f1.x); h1.y = f2bf(f1.y); h1.z = f2bf(f1.z); h1.w = f2bf(f1.w);
      *reinterpret_cast<ushort4*>(&As[r * 72 + kc * 8])     = h0;
      *reinterpret_cast<ushort4*>(&As[r * 72 + kc * 8 + 4]) = h1;
      uint4 vb = *reinterpret_cast<const uint4*>(Wb + (ncol + r) * 256 + kt * 64 + kc * 8);
      *reinterpret_cast<uint4*>(&Bs[r * 72 + kc * 8]) = vb;
    }
    __syncthreads();
#pragma unroll
    for (int ks = 0; ks < 2; ++ks) {
      bf16x8 af[4], bf[4];
#pragma unroll
      for (int m = 0; m < 4; ++m)
        af[m] = *reinterpret_cast<const bf16x8*>(&As[(waveM + m * 16 + (lane & 15)) * 72 + ks * 32 + (lane >> 4) * 8]);
#pragma unroll
      for (int n = 0; n < 4; ++n)
        bf[n] = *reinterpret_cast<const bf16x8*>(&Bs[(waveN + n * 16 + (lane & 15)) * 72 + ks * 32 + (lane >> 4) * 8]);
#pragma unroll
      for (int m = 0; m < 4; ++m)
#pragma unroll
        for (int n = 0; n < 4; ++n) acc[m][n] = mfma16(af[m], bf[n], acc[m][n]);
    }
  }
#pragma unroll
  for (int m = 0; m < 4; ++m)
#pragma unroll
    for (int n = 0; n < 4; ++n) {
      int j = ncol + waveN + n * 16 + (lane & 15);
      float bias_v = bias[j] * bscale;
      int h = j >> 5, d = j & 31;
      int i0 = bm + waveM + m * 16 + (lane >> 4) * 4;  // row of r=0 (mult of 4)
      int b = i0 >> 11, s = i0 & 2047;
      if (mat == 2) {
        ushort4 ww = *reinterpret_cast<const ushort4*>(&wb[s]);
        ushort4 pk;
        pk.x = f2bf((acc[m][n][0] + bias_v) * bfbits2f(ww.x));
        pk.y = f2bf((acc[m][n][1] + bias_v) * bfbits2f(ww.y));
        pk.z = f2bf((acc[m][n][2] + bias_v) * bfbits2f(ww.z));
        pk.w = f2bf((acc[m][n][3] + bias_v) * bfbits2f(ww.w));
        *reinterpret_cast<ushort4*>(&Vt[((b * NHEAD + h) * DK + d) * SEQ + s]) = pk;
      } else {
        unsigned short* dst = (mat == 0) ? Qb : Kb;
#pragma unroll
        for (int r = 0; r < 4; ++r)
          dst[((b * NHEAD + h) * SEQ + s + r) * DK + d] = f2bf(acc[m][n][r] + bias_v);
      }
    }
}

// ---------------- fused weighted attention (16x16 MFMA, dbuf P, union LDS) ---
// Round-8 passing structure. ONE change: the per-wave P scratch (2x2560B) and
// the per-wave output-combine tile (32x36 f32 = 4608B) share one 5120B region.
// Safety: __syncthreads() between the last P read and the overlay writes (and
// before cross-wave reads) — LDS ops cannot be scheduled across s_barrier, so
// the float/ushort TBAA no-alias assumption (round-6 failure theory) cannot
// reorder traffic across the switchover. LDS: 38912 -> 20480 B => 7 blocks/CU.
__global__ __launch_bounds__(256, 4) void attn_kernel(
    const unsigned short* __restrict__ Qb, const unsigned short* __restrict__ Kb,
    const unsigned short* __restrict__ Vt, const unsigned short* __restrict__ wb,
    unsigned short* __restrict__ AOb) {
  __shared__ __align__(16) unsigned char smem[4][5120];
  const int tid = threadIdx.x, lane = tid & 63, wid = tid >> 6;
  const int g = lane >> 4, lq = lane & 15;
  const int bh = blockIdx.y;
  const int q0 = blockIdx.x * 32;

  unsigned short* pbuf = reinterpret_cast<unsigned short*>(&smem[wid][0]);

  const unsigned short* Qbh = Qb + bh * SEQ * DK;
  const unsigned short* Kbh = Kb + bh * SEQ * DK;
  const unsigned short* Vbh = Vt + bh * DK * SEQ;

  bf16x8 qf[2];
  qf[0] = *reinterpret_cast<const bf16x8*>(Qbh + (q0 + lq) * DK + g * 8);
  qf[1] = *reinterpret_cast<const bf16x8*>(Qbh + (q0 + 16 + lq) * DK + g * 8);

  f32x4 o[2][2] = {};   // [q-tile m][d-tile n]
  f32x4 den[2] = {};
  const f32x4 zero4 = {0.f, 0.f, 0.f, 0.f};
  const int sbase = wid * (SEQ / 4);

#pragma unroll 2
  for (int st = 0; st < (SEQ / 4) / 32; ++st) {
    const int s0 = sbase + st * 32;
    bf16x8 kf0 = *reinterpret_cast<const bf16x8*>(Kbh + (s0 + lq) * DK + g * 8);
    bf16x8 kf1 = *reinterpret_cast<const bf16x8*>(Kbh + (s0 + 16 + lq) * DK + g * 8);

    unsigned short* pb = pbuf + (st & 1) * 1280;   // ping-pong, 2560B each

    // QK^T + exp + pack P^T into LDS: row q32 = 16m+lq, cols s' = 4g+r / 16+4g+r
#pragma unroll
    for (int m = 0; m < 2; ++m) {
      f32x4 sc0 = mfma16(kf0, qf[m], zero4);
      f32x4 sc1 = mfma16(kf1, qf[m], zero4);
      uint2 w0, w1;
      w0.x = cvtpk(__builtin_amdgcn_exp2f(sc0[0]), __builtin_amdgcn_exp2f(sc0[1]));
      w0.y = cvtpk(__builtin_amdgcn_exp2f(sc0[2]), __builtin_amdgcn_exp2f(sc0[3]));
      w1.x = cvtpk(__builtin_amdgcn_exp2f(sc1[0]), __builtin_amdgcn_exp2f(sc1[1]));
      w1.y = cvtpk(__builtin_amdgcn_exp2f(sc1[2]), __builtin_amdgcn_exp2f(sc1[3]));
      *reinterpret_cast<uint2*>(pb + (16 * m + lq) * 40 + g * 4)      = w0;
      *reinterpret_cast<uint2*>(pb + (16 * m + lq) * 40 + 16 + g * 4) = w1;
    }

    bf16x8 vf0 = *reinterpret_cast<const bf16x8*>(Vbh + (lq)      * SEQ + s0 + g * 8);
    bf16x8 vf1 = *reinterpret_cast<const bf16x8*>(Vbh + (16 + lq) * SEQ + s0 + g * 8);
    bf16x8 wf  = *reinterpret_cast<const bf16x8*>(wb + s0 + g * 8);

#pragma unroll
    for (int m = 0; m < 2; ++m) {
      bf16x8 pa = *reinterpret_cast<const bf16x8*>(pb + (16 * m + lq) * 40 + g * 8);
      o[m][0] = mfma16(pa, vf0, o[m][0]);
      o[m][1] = mfma16(pa, vf1, o[m][1]);
      den[m]  = mfma16(pa, wf,  den[m]);
    }
  }

  // fence: all P-scratch traffic complete before the float overlay is written
  __syncthreads();

  float (*olw)[36] = reinterpret_cast<float(*)[36]>(&smem[wid][0]);
#pragma unroll
  for (int m = 0; m < 2; ++m) {
#pragma unroll
    for (int r = 0; r < 4; ++r) {
      int q32 = 16 * m + 4 * g + r;
      olw[q32][lq]      = o[m][0][r];
      olw[q32][16 + lq] = o[m][1][r];
      if (lq == 0) olw[q32][32] = den[m][r];
    }
  }
  __syncthreads();

  const int b = bh >> 3, h = bh & 7;
  for (int idx = tid; idx < 32 * 32; idx += 256) {
    int q = idx >> 5, d = idx & 31;
    float num = 0.f, dd = 0.f;
#pragma unroll
    for (int w = 0; w < 4; ++w) {
      float (*olr)[36] = reinterpret_cast<float(*)[36]>(&smem[w][0]);
      num += olr[q][d];
      dd  += olr[q][32];
    }
    AOb[(b * SEQ + q0 + q) * D_MODEL + h * DK + d] = f2bf(num / dd);
  }
}

// ---------------- output projection GEMM (fp32 out + bias) ----------------
__global__ __launch_bounds__(256) void out_gemm(
    const unsigned short* __restrict__ Ab, const unsigned short* __restrict__ Wob,
    const float* __restrict__ bo, float* __restrict__ out) {
  __shared__ __align__(16) unsigned short As[128 * 72];
  __shared__ __align__(16) unsigned short Bs[128 * 72];
  const int tid = threadIdx.x, lane = tid & 63, wid = tid >> 6;
  const int bm = blockIdx.x * 128;
  const int ncol = blockIdx.y * 128;
  const int waveM = (wid >> 1) * 64, waveN = (wid & 1) * 64;

  f32x4 acc[4][4] = {};
  for (int kt = 0; kt < 4; ++kt) {
    __syncthreads();
#pragma unroll
    for (int p = 0; p < 4; ++p) {
      int c = p * 256 + tid;
      int r = c >> 3, kc = c & 7;
      uint4 va = *reinterpret_cast<const uint4*>(Ab + (bm + r) * 256 + kt * 64 + kc * 8);
      *reinterpret_cast<uint4*>(&As[r * 72 + kc * 8]) = va;
      uint4 vb = *reinterpret_cast<const uint4*>(Wob + (ncol + r) * 256 + kt * 64 + kc * 8);
      *reinterpret_cast<uint4*>(&Bs[r * 72 + kc * 8]) = vb;
    }
    __syncthreads();
#pragma unroll
    for (int ks = 0; ks < 2; ++ks) {
      bf16x8 af[4], bf[4];
#pragma unroll
      for (int m = 0; m < 4; ++m)
        af[m] = *reinterpret_cast<const bf16x8*>(&As[(waveM + m * 16 + (lane & 15)) * 72 + ks * 32 + (lane >> 4) * 8]);
#pragma unroll
      for (int n = 0; n < 4; ++n)
        bf[n] = *reinterpret_cast<const bf16x8*>(&Bs[(waveN + n * 16 + (lane & 15)) * 72 + ks * 32 + (lane >> 4) * 8]);
#pragma unroll
      for (int m = 0; m < 4; ++m)
#pragma unroll
        for (int n = 0; n < 4; ++n) acc[m][n] = mfma16(af[m], bf[n], acc[m][n]);
    }
  }
#pragma unroll
  for (int m = 0; m < 4; ++m)
#pragma unroll
    for (int n = 0; n < 4; ++n) {
      int j = ncol + waveN + n * 16 + (lane & 15);
      float bias_v = bo[j];
#pragma unroll
      for (int r = 0; r < 4; ++r) {
        int i = bm + waveM + m * 16 + (lane >> 4) * 4 + r;
        out[i * D_MODEL + j] = acc[m][n][r] + bias_v;
      }
    }
}

// ---------------- launcher ----------------
extern "C" void kernel_launch(void* const* d_in, const int* in_sizes, int n_in,
                              void* d_out, int out_size, void* d_ws, size_t ws_size,
                              hipStream_t stream) {
  const float* x  = (const float*)d_in[0];
  const float* cx = (const float*)d_in[1];
  const float* Wq = (const float*)d_in[2];
  const float* bq = (const float*)d_in[3];
  const float* Wk = (const float*)d_in[4];
  const float* bk = (const float*)d_in[5];
  const float* Wv = (const float*)d_in[6];
  const float* bv = (const float*)d_in[7];
  const float* Wo = (const float*)d_in[8];
  const float* bo = (const float*)d_in[9];
  float* out = (float*)d_out;
  char* ws = (char*)d_ws;

  unsigned short* Qb  = (unsigned short*)(ws + (size_t)4  * 1024 * 1024);
  unsigned short* Kb  = (unsigned short*)(ws + (size_t)8  * 1024 * 1024);
  unsigned short* Vt  = (unsigned short*)(ws + (size_t)12 * 1024 * 1024);
  unsigned short* AOb = (unsigned short*)(ws + (size_t)16 * 1024 * 1024);
  unsigned short* Wqb = (unsigned short*)(ws + (size_t)20 * 1024 * 1024);
  unsigned short* Wkb = Wqb + 65536;
  unsigned short* Wvb = Wkb + 65536;
  unsigned short* Wob = Wvb + 65536;
  unsigned short* wb  = (unsigned short*)(ws + (size_t)21 * 1024 * 1024);

  prep_kernel<<<64, 256, 0, stream>>>(cx, Wq, Wk, Wv, Wo, Wqb, Wkb, Wvb, Wob, wb);
  qkv_gemm<<<dim3(64, 6), 256, 0, stream>>>(x, Wqb, Wkb, Wvb, bq, bk, bv, wb, Qb, Kb, Vt);
  attn_kernel<<<dim3(64, 32), 256, 0, stream>>>(Qb, Kb, Vt, wb, AOb);
  out_gemm<<<dim3(64, 2), 256, 0, stream>>>(AOb, Wob, bo, out);
}

// Round 10
// 89.876 us; speedup vs baseline: 1.0066x; 1.0066x over previous
//
#include <hip/hip_runtime.h>
#include <hip/hip_bf16.h>
#include <stdint.h>

#define D_MODEL 256
#define NHEAD   8
#define DK      32
#define BATCH   4
#define SEQ     2048
#define MROWS   (BATCH*SEQ)   // 8192

typedef float  f32x4  __attribute__((ext_vector_type(4)));
typedef __bf16 bf16x8 __attribute__((ext_vector_type(8)));

__device__ __forceinline__ unsigned short f2bf(float f) {
  unsigned int u = __float_as_uint(f);
  unsigned int r = (u + 0x7FFFu + ((u >> 16) & 1u)) >> 16;
  return (unsigned short)r;
}
__device__ __forceinline__ float bfbits2f(unsigned short b) {
  return __uint_as_float(((unsigned int)b) << 16);
}

__device__ __forceinline__ f32x4 mfma16(bf16x8 a, bf16x8 b, f32x4 c) {
  return __builtin_amdgcn_mfma_f32_16x16x32_bf16(a, b, c, 0, 0, 0);
}
__device__ __forceinline__ unsigned int cvtpk(float lo, float hi) {
  unsigned int r;
  asm("v_cvt_pk_bf16_f32 %0, %1, %2" : "=v"(r) : "v"(lo), "v"(hi));
  return r;
}

// scale folded into Wq/bq: (1/sqrt(32)) * log2(e)
#define QSCALE 0.2550599440097021f

// ---------------- prep: W fp32->bf16 casts + coordinate weights --------------
__global__ void prep_kernel(const float* __restrict__ cx,
                            const float* __restrict__ Wq, const float* __restrict__ Wk,
                            const float* __restrict__ Wv, const float* __restrict__ Wo,
                            unsigned short* __restrict__ Wqb, unsigned short* __restrict__ Wkb,
                            unsigned short* __restrict__ Wvb, unsigned short* __restrict__ Wob,
                            unsigned short* __restrict__ wb) {
  int tid = blockIdx.x * blockDim.x + threadIdx.x;
  int nthr = gridDim.x * blockDim.x;
  const int nw4 = (D_MODEL * D_MODEL) / 4;  // 16384
  for (int i = tid; i < nw4; i += nthr) {
    float4 a = reinterpret_cast<const float4*>(Wq)[i];
    ushort4 oa; oa.x = f2bf(a.x * QSCALE); oa.y = f2bf(a.y * QSCALE);
    oa.z = f2bf(a.z * QSCALE); oa.w = f2bf(a.w * QSCALE);
    reinterpret_cast<ushort4*>(Wqb)[i] = oa;
    float4 b = reinterpret_cast<const float4*>(Wk)[i];
    ushort4 ob; ob.x = f2bf(b.x); ob.y = f2bf(b.y); ob.z = f2bf(b.z); ob.w = f2bf(b.w);
    reinterpret_cast<ushort4*>(Wkb)[i] = ob;
    float4 c = reinterpret_cast<const float4*>(Wv)[i];
    ushort4 oc; oc.x = f2bf(c.x); oc.y = f2bf(c.y); oc.z = f2bf(c.z); oc.w = f2bf(c.w);
    reinterpret_cast<ushort4*>(Wvb)[i] = oc;
    float4 d = reinterpret_cast<const float4*>(Wo)[i];
    ushort4 od; od.x = f2bf(d.x); od.y = f2bf(d.y); od.z = f2bf(d.z); od.w = f2bf(d.w);
    reinterpret_cast<ushort4*>(Wob)[i] = od;
  }
  for (int i = tid; i < SEQ; i += nthr)
    wb[i] = (i == 0) ? (unsigned short)0 : f2bf(fabsf(cx[i] - cx[i - 1]));
}

// ---------------- fused QKV projection GEMM (x cast fused in staging) --------
// Q/K out: [bh][s][32]; V out: transposed + w-scaled: Vt[bh][d][s] = w_s * V[s][d].
__global__ __launch_bounds__(256) void qkv_gemm(
    const float* __restrict__ x,
    const unsigned short* __restrict__ Wqb, const unsigned short* __restrict__ Wkb,
    const unsigned short* __restrict__ Wvb,
    const float* __restrict__ bq, const float* __restrict__ bk_, const float* __restrict__ bv,
    const unsigned short* __restrict__ wb,
    unsigned short* __restrict__ Qb, unsigned short* __restrict__ Kb, unsigned short* __restrict__ Vt) {
  __shared__ __align__(16) unsigned short As[128 * 72];
  __shared__ __align__(16) unsigned short Bs[128 * 72];
  const int tid = threadIdx.x, lane = tid & 63, wid = tid >> 6;
  const int bm = blockIdx.x * 128;
  const int mat = blockIdx.y >> 1;
  const int ncol = (blockIdx.y & 1) * 128;
  const unsigned short* Wb = (mat == 0) ? Wqb : ((mat == 1) ? Wkb : Wvb);
  const float* bias = (mat == 0) ? bq : ((mat == 1) ? bk_ : bv);
  const float bscale = (mat == 0) ? QSCALE : 1.0f;
  const int waveM = (wid >> 1) * 64, waveN = (wid & 1) * 64;

  f32x4 acc[4][4] = {};
  for (int kt = 0; kt < 4; ++kt) {
    __syncthreads();
#pragma unroll
    for (int p = 0; p < 4; ++p) {
      int c = p * 256 + tid;
      int r = c >> 3, kc = c & 7;
      const float* xp = x + (size_t)(bm + r) * 256 + kt * 64 + kc * 8;
      float4 f0 = *reinterpret_cast<const float4*>(xp);
      float4 f1 = *reinterpret_cast<const float4*>(xp + 4);
      ushort4 h0, h1;
      h0.x = f2bf(f0.x); h0.y = f2bf(f0.y); h0.z = f2bf(f0.z); h0.w = f2bf(f0.w);
      h1.x = f2bf(f1.x); h1.y = f2bf(f1.y); h1.z = f2bf(f1.z); h1.w = f2bf(f1.w);
      *reinterpret_cast<ushort4*>(&As[r * 72 + kc * 8])     = h0;
      *reinterpret_cast<ushort4*>(&As[r * 72 + kc * 8 + 4]) = h1;
      uint4 vb = *reinterpret_cast<const uint4*>(Wb + (ncol + r) * 256 + kt * 64 + kc * 8);
      *reinterpret_cast<uint4*>(&Bs[r * 72 + kc * 8]) = vb;
    }
    __syncthreads();
#pragma unroll
    for (int ks = 0; ks < 2; ++ks) {
      bf16x8 af[4], bf[4];
#pragma unroll
      for (int m = 0; m < 4; ++m)
        af[m] = *reinterpret_cast<const bf16x8*>(&As[(waveM + m * 16 + (lane & 15)) * 72 + ks * 32 + (lane >> 4) * 8]);
#pragma unroll
      for (int n = 0; n < 4; ++n)
        bf[n] = *reinterpret_cast<const bf16x8*>(&Bs[(waveN + n * 16 + (lane & 15)) * 72 + ks * 32 + (lane >> 4) * 8]);
#pragma unroll
      for (int m = 0; m < 4; ++m)
#pragma unroll
        for (int n = 0; n < 4; ++n) acc[m][n] = mfma16(af[m], bf[n], acc[m][n]);
    }
  }
#pragma unroll
  for (int m = 0; m < 4; ++m)
#pragma unroll
    for (int n = 0; n < 4; ++n) {
      int j = ncol + waveN + n * 16 + (lane & 15);
      float bias_v = bias[j] * bscale;
      int h = j >> 5, d = j & 31;
      int i0 = bm + waveM + m * 16 + (lane >> 4) * 4;  // row of r=0 (mult of 4)
      int b = i0 >> 11, s = i0 & 2047;
      if (mat == 2) {
        ushort4 ww = *reinterpret_cast<const ushort4*>(&wb[s]);
        ushort4 pk;
        pk.x = f2bf((acc[m][n][0] + bias_v) * bfbits2f(ww.x));
        pk.y = f2bf((acc[m][n][1] + bias_v) * bfbits2f(ww.y));
        pk.z = f2bf((acc[m][n][2] + bias_v) * bfbits2f(ww.z));
        pk.w = f2bf((acc[m][n][3] + bias_v) * bfbits2f(ww.w));
        *reinterpret_cast<ushort4*>(&Vt[((b * NHEAD + h) * DK + d) * SEQ + s]) = pk;
      } else {
        unsigned short* dst = (mat == 0) ? Qb : Kb;
#pragma unroll
        for (int r = 0; r < 4; ++r)
          dst[((b * NHEAD + h) * SEQ + s + r) * DK + d] = f2bf(acc[m][n][r] + bias_v);
      }
    }
}

// ---------------- fused weighted attention (r8 base + explicit prefetch) -----
// Round-8 passing structure (dbuf'd dedicated P scratch, separate ol array).
// ONE change: explicit 1-step-ahead global prefetch — two named register sets
// (A/B) for {K0,K1,V0,V1,w}; loads for step i+1 are issued BEFORE step i's
// compute, so global latency hides under QK/exp/PV instead of heading each
// step's dependence chain (round-9 counters: VGPR=48 => compiler wasn't
// prefetching; all pipes idle => latency-bound at the chain top).
__global__ __launch_bounds__(256, 4) void attn_kernel(
    const unsigned short* __restrict__ Qb, const unsigned short* __restrict__ Kb,
    const unsigned short* __restrict__ Vt, const unsigned short* __restrict__ wb,
    unsigned short* __restrict__ AOb) {
  __shared__ float ol[4][32][36];
  __shared__ __align__(16) unsigned short ps[4][2][32][40];
  const int tid = threadIdx.x, lane = tid & 63, wid = tid >> 6;
  const int g = lane >> 4, lq = lane & 15;
  const int bh = blockIdx.y;
  const int q0 = blockIdx.x * 32;

  const unsigned short* Qbh = Qb + bh * SEQ * DK;
  const unsigned short* Kbh = Kb + bh * SEQ * DK;
  const unsigned short* Vbh = Vt + bh * DK * SEQ;

  bf16x8 qf[2];
  qf[0] = *reinterpret_cast<const bf16x8*>(Qbh + (q0 + lq) * DK + g * 8);
  qf[1] = *reinterpret_cast<const bf16x8*>(Qbh + (q0 + 16 + lq) * DK + g * 8);

  f32x4 o[2][2] = {};   // [q-tile m][d-tile n]
  f32x4 den[2] = {};
  const f32x4 zero4 = {0.f, 0.f, 0.f, 0.f};
  const int sbase = wid * (SEQ / 4);

  auto loads = [&](int st, bf16x8& k0, bf16x8& k1, bf16x8& v0, bf16x8& v1, bf16x8& ww) {
    const int s0 = sbase + st * 32;
    k0 = *reinterpret_cast<const bf16x8*>(Kbh + (s0 + lq) * DK + g * 8);
    k1 = *reinterpret_cast<const bf16x8*>(Kbh + (s0 + 16 + lq) * DK + g * 8);
    v0 = *reinterpret_cast<const bf16x8*>(Vbh + (lq)      * SEQ + s0 + g * 8);
    v1 = *reinterpret_cast<const bf16x8*>(Vbh + (16 + lq) * SEQ + s0 + g * 8);
    ww = *reinterpret_cast<const bf16x8*>(wb + s0 + g * 8);
  };

  auto step = [&](bf16x8 k0, bf16x8 k1, bf16x8 v0, bf16x8 v1, bf16x8 ww,
                  unsigned short* pb) {
    // QK^T + exp + pack P^T into LDS: row q32 = 16m+lq, cols s' = 4g+r / 16+4g+r
#pragma unroll
    for (int m = 0; m < 2; ++m) {
      f32x4 sc0 = mfma16(k0, qf[m], zero4);
      f32x4 sc1 = mfma16(k1, qf[m], zero4);
      uint2 w0, w1;
      w0.x = cvtpk(__builtin_amdgcn_exp2f(sc0[0]), __builtin_amdgcn_exp2f(sc0[1]));
      w0.y = cvtpk(__builtin_amdgcn_exp2f(sc0[2]), __builtin_amdgcn_exp2f(sc0[3]));
      w1.x = cvtpk(__builtin_amdgcn_exp2f(sc1[0]), __builtin_amdgcn_exp2f(sc1[1]));
      w1.y = cvtpk(__builtin_amdgcn_exp2f(sc1[2]), __builtin_amdgcn_exp2f(sc1[3]));
      *reinterpret_cast<uint2*>(pb + (16 * m + lq) * 40 + g * 4)      = w0;
      *reinterpret_cast<uint2*>(pb + (16 * m + lq) * 40 + 16 + g * 4) = w1;
    }
#pragma unroll
    for (int m = 0; m < 2; ++m) {
      bf16x8 pa = *reinterpret_cast<const bf16x8*>(pb + (16 * m + lq) * 40 + g * 8);
      o[m][0] = mfma16(pa, v0, o[m][0]);
      o[m][1] = mfma16(pa, v1, o[m][1]);
      den[m]  = mfma16(pa, ww, den[m]);
    }
  };

  bf16x8 kA0, kA1, vA0, vA1, wA;
  bf16x8 kB0, kB1, vB0, vB1, wB;
  loads(0, kA0, kA1, vA0, vA1, wA);

  for (int st = 0; st < 16; st += 2) {
    loads(st + 1, kB0, kB1, vB0, vB1, wB);          // prefetch odd step
    step(kA0, kA1, vA0, vA1, wA, &ps[wid][0][0][0]);
    if (st + 2 < 16)
      loads(st + 2, kA0, kA1, vA0, vA1, wA);        // prefetch next even step
    step(kB0, kB1, vB0, vB1, wB, &ps[wid][1][0][0]);
  }

  // stash partials into ol[wid]: [q32][d], denominator in col 32
#pragma unroll
  for (int m = 0; m < 2; ++m) {
#pragma unroll
    for (int r = 0; r < 4; ++r) {
      int q32 = 16 * m + 4 * g + r;
      ol[wid][q32][lq]      = o[m][0][r];
      ol[wid][q32][16 + lq] = o[m][1][r];
      if (lq == 0) ol[wid][q32][32] = den[m][r];
    }
  }
  __syncthreads();

  const int b = bh >> 3, h = bh & 7;
  for (int idx = tid; idx < 32 * 32; idx += 256) {
    int q = idx >> 5, d = idx & 31;
    float num = ol[0][q][d] + ol[1][q][d] + ol[2][q][d] + ol[3][q][d];
    float dd  = ol[0][q][32] + ol[1][q][32] + ol[2][q][32] + ol[3][q][32];
    AOb[(b * SEQ + q0 + q) * D_MODEL + h * DK + d] = f2bf(num / dd);
  }
}

// ---------------- output projection GEMM (fp32 out + bias) ----------------
__global__ __launch_bounds__(256) void out_gemm(
    const unsigned short* __restrict__ Ab, const unsigned short* __restrict__ Wob,
    const float* __restrict__ bo, float* __restrict__ out) {
  __shared__ __align__(16) unsigned short As[128 * 72];
  __shared__ __align__(16) unsigned short Bs[128 * 72];
  const int tid = threadIdx.x, lane = tid & 63, wid = tid >> 6;
  const int bm = blockIdx.x * 128;
  const int ncol = blockIdx.y * 128;
  const int waveM = (wid >> 1) * 64, waveN = (wid & 1) * 64;

  f32x4 acc[4][4] = {};
  for (int kt = 0; kt < 4; ++kt) {
    __syncthreads();
#pragma unroll
    for (int p = 0; p < 4; ++p) {
      int c = p * 256 + tid;
      int r = c >> 3, kc = c & 7;
      uint4 va = *reinterpret_cast<const uint4*>(Ab + (bm + r) * 256 + kt * 64 + kc * 8);
      *reinterpret_cast<uint4*>(&As[r * 72 + kc * 8]) = va;
      uint4 vb = *reinterpret_cast<const uint4*>(Wob + (ncol + r) * 256 + kt * 64 + kc * 8);
      *reinterpret_cast<uint4*>(&Bs[r * 72 + kc * 8]) = vb;
    }
    __syncthreads();
#pragma unroll
    for (int ks = 0; ks < 2; ++ks) {
      bf16x8 af[4], bf[4];
#pragma unroll
      for (int m = 0; m < 4; ++m)
        af[m] = *reinterpret_cast<const bf16x8*>(&As[(waveM + m * 16 + (lane & 15)) * 72 + ks * 32 + (lane >> 4) * 8]);
#pragma unroll
      for (int n = 0; n < 4; ++n)
        bf[n] = *reinterpret_cast<const bf16x8*>(&Bs[(waveN + n * 16 + (lane & 15)) * 72 + ks * 32 + (lane >> 4) * 8]);
#pragma unroll
      for (int m = 0; m < 4; ++m)
#pragma unroll
        for (int n = 0; n < 4; ++n) acc[m][n] = mfma16(af[m], bf[n], acc[m][n]);
    }
  }
#pragma unroll
  for (int m = 0; m < 4; ++m)
#pragma unroll
    for (int n = 0; n < 4; ++n) {
      int j = ncol + waveN + n * 16 + (lane & 15);
      float bias_v = bo[j];
#pragma unroll
      for (int r = 0; r < 4; ++r) {
        int i = bm + waveM + m * 16 + (lane >> 4) * 4 + r;
        out[i * D_MODEL + j] = acc[m][n][r] + bias_v;
      }
    }
}

// ---------------- launcher ----------------
extern "C" void kernel_launch(void* const* d_in, const int* in_sizes, int n_in,
                              void* d_out, int out_size, void* d_ws, size_t ws_size,
                              hipStream_t stream) {
  const float* x  = (const float*)d_in[0];
  const float* cx = (const float*)d_in[1];
  const float* Wq = (const float*)d_in[2];
  const float* bq = (const float*)d_in[3];
  const float* Wk = (const float*)d_in[4];
  const float* bk = (const float*)d_in[5];
  const float* Wv = (const float*)d_in[6];
  const float* bv = (const float*)d_in[7];
  const float* Wo = (const float*)d_in[8];
  const float* bo = (const float*)d_in[9];
  float* out = (float*)d_out;
  char* ws = (char*)d_ws;

  unsigned short* Qb  = (unsigned short*)(ws + (size_t)4  * 1024 * 1024);
  unsigned short* Kb  = (unsigned short*)(ws + (size_t)8  * 1024 * 1024);
  unsigned short* Vt  = (unsigned short*)(ws + (size_t)12 * 1024 * 1024);
  unsigned short* AOb = (unsigned short*)(ws + (size_t)16 * 1024 * 1024);
  unsigned short* Wqb = (unsigned short*)(ws + (size_t)20 * 1024 * 1024);
  unsigned short* Wkb = Wqb + 65536;
  unsigned short* Wvb = Wkb + 65536;
  unsigned short* Wob = Wvb + 65536;
  unsigned short* wb  = (unsigned short*)(ws + (size_t)21 * 1024 * 1024);

  prep_kernel<<<64, 256, 0, stream>>>(cx, Wq, Wk, Wv, Wo, Wqb, Wkb, Wvb, Wob, wb);
  qkv_gemm<<<dim3(64, 6), 256, 0, stream>>>(x, Wqb, Wkb, Wvb, bq, bk, bv, wb, Qb, Kb, Vt);
  attn_kernel<<<dim3(64, 32), 256, 0, stream>>>(Qb, Kb, Vt, wb, AOb);
  out_gemm<<<dim3(64, 2), 256, 0, stream>>>(AOb, Wob, bo, out);
}